// Round 1
// baseline (1286.547 us; speedup 1.0000x reference)
//
#include <hip/hip_runtime.h>
#include <hip/hip_bf16.h>

// Deep Hough transform, gather/CSR formulation.
// Sizes fixed by setup_inputs(): N=8, C=128, H=W=128, A=R=120.
#define NC    1024
#define HW    16384
#define HH    128
#define WW    128
#define NA    120
#define NR    120
#define PI_D  3.14159265358979323846

// ---------------- workspace layout (bytes) ----------------
// featT : HW x NC fp32           = 67,108,864
// outT  : (NA*NR) x NC fp32      = 58,982,400
// plist : NA x HW uint16         =  3,932,160
// tabs  : 2*NA fp32
// cnts  : NA*NR int32
// offs  : NA*(NR+1) int32
#define WS_FEATT   0UL
#define WS_OUTT    67108864UL
#define WS_PLIST   (67108864UL + 58982400UL)            // 126,091,264
#define WS_TABS    (126091264UL + 3932160UL)            // 130,023,424
#define WS_CNTS    (130023424UL + 1024UL)               // 130,024,448
#define WS_OFFS    (130024448UL + 57600UL + 64UL)       // 130,082,112

// ---- K0: cos/sin tables, fp64 exactly like numpy then cast to f32 ----
__global__ void k_tab(float* __restrict__ tabs) {
    int a = threadIdx.x;
    if (a < NA) {
        double itheta = PI_D / (double)NA;
        double diag   = sqrt((double)(HH * HH + WW * WW));      // 181.019...
        double irho   = floor(diag + 1.0) / (double)(NR - 1);   // 182/119
        double ang    = (double)a * itheta;
        tabs[a]       = (float)(cos(ang) / irho);
        tabs[NA + a]  = (float)(sin(ang) / irho);
    }
}

// rho bin for pixel p at angle tabs — MUST match numpy: f32 mul, f32 mul,
// f32 add (no fma contraction), round-half-even, +NR/2, clip.
__device__ __forceinline__ int rho_bin(int p, float tc, float ts) {
#pragma clang fp contract(off)
    int y = p >> 7, x = p & (WW - 1);
    float u = (float)(x - WW / 2) * tc;
    float v = (float)(y - HH / 2) * ts;
    float s = u + v;
    int r = (int)rintf(s) + NR / 2;
    return min(NR - 1, max(0, r));
}

// ---- K1: per-angle histogram of bin counts ----
__global__ __launch_bounds__(256) void k_count(const float* __restrict__ tabs,
                                               int* __restrict__ cnts) {
    __shared__ int cnt[NR];
    int a = blockIdx.x, t = threadIdx.x;
    if (t < NR) cnt[t] = 0;
    __syncthreads();
    float tc = tabs[a], ts = tabs[NA + a];
    for (int p = t; p < HW; p += 256)
        atomicAdd(&cnt[rho_bin(p, tc, ts)], 1);
    __syncthreads();
    if (t < NR) cnts[a * NR + t] = cnt[t];
}

// ---- K2: exclusive scan per angle (one thread per angle) ----
__global__ void k_scan(const int* __restrict__ cnts, int* __restrict__ offs) {
    int a = threadIdx.x;
    if (a < NA) {
        int base = 0;
        for (int r = 0; r < NR; ++r) {
            offs[a * (NR + 1) + r] = base;
            base += cnts[a * NR + r];
        }
        offs[a * (NR + 1) + NR] = base;   // == HW
    }
}

// ---- K3: counting-sort scatter of pixel ids into CSR list ----
__global__ __launch_bounds__(256) void k_scatter(const float* __restrict__ tabs,
                                                 const int* __restrict__ offs,
                                                 unsigned short* __restrict__ plist) {
    __shared__ int cur[NR];
    int a = blockIdx.x, t = threadIdx.x;
    if (t < NR) cur[t] = offs[a * (NR + 1) + t];
    __syncthreads();
    float tc = tabs[a], ts = tabs[NA + a];
    for (int p = t; p < HW; p += 256) {
        int r = rho_bin(p, tc, ts);
        int pos = atomicAdd(&cur[r], 1);
        plist[a * HW + pos] = (unsigned short)p;
    }
}

// ---- K4: transpose feat (NC x HW) -> featT (HW x NC) ----
__global__ __launch_bounds__(256) void k_tr_in(const float* __restrict__ in,
                                               float* __restrict__ outp) {
    __shared__ float tile[32][33];
    int p0 = blockIdx.x * 32;          // pixel tile
    int c0 = blockIdx.y * 32;          // channel tile
    int tx = threadIdx.x, ty = threadIdx.y;   // 32 x 8
    for (int i = 0; i < 32; i += 8)
        tile[ty + i][tx] = in[(size_t)(c0 + ty + i) * HW + p0 + tx];
    __syncthreads();
    for (int i = 0; i < 32; i += 8)
        outp[(size_t)(p0 + ty + i) * NC + c0 + tx] = tile[tx][ty + i];
}

// ---- K5: main gather. block = (rho-chunk, angle), thread t = 4 channels ----
#define R_PER_BLK 8
__global__ __launch_bounds__(256) void k_gather(const float4* __restrict__ featT4,
                                                const int* __restrict__ offs,
                                                const unsigned short* __restrict__ plist,
                                                float4* __restrict__ outT4) {
    const int a  = blockIdx.y;
    const int r0 = blockIdx.x * R_PER_BLK;
    const int t  = threadIdx.x;               // 256 threads x float4 = 1024 nc
    const unsigned short* pl = plist + (size_t)a * HW;
    for (int r = r0; r < r0 + R_PER_BLK; ++r) {
        int k0 = offs[a * (NR + 1) + r];
        int k1 = offs[a * (NR + 1) + r + 1];
        float4 a0 = {0.f, 0.f, 0.f, 0.f}, a1 = a0, a2 = a0, a3 = a0;
        int k = k0;
        for (; k + 4 <= k1; k += 4) {
            int p0 = pl[k], p1 = pl[k + 1], p2 = pl[k + 2], p3 = pl[k + 3];
            float4 v0 = featT4[(size_t)p0 * 256 + t];
            float4 v1 = featT4[(size_t)p1 * 256 + t];
            float4 v2 = featT4[(size_t)p2 * 256 + t];
            float4 v3 = featT4[(size_t)p3 * 256 + t];
            a0.x += v0.x; a0.y += v0.y; a0.z += v0.z; a0.w += v0.w;
            a1.x += v1.x; a1.y += v1.y; a1.z += v1.z; a1.w += v1.w;
            a2.x += v2.x; a2.y += v2.y; a2.z += v2.z; a2.w += v2.w;
            a3.x += v3.x; a3.y += v3.y; a3.z += v3.z; a3.w += v3.w;
        }
        for (; k < k1; ++k) {
            float4 v = featT4[(size_t)pl[k] * 256 + t];
            a0.x += v.x; a0.y += v.y; a0.z += v.z; a0.w += v.w;
        }
        float4 s;
        s.x = (a0.x + a1.x) + (a2.x + a3.x);
        s.y = (a0.y + a1.y) + (a2.y + a3.y);
        s.z = (a0.z + a1.z) + (a2.z + a3.z);
        s.w = (a0.w + a1.w) + (a2.w + a3.w);
        outT4[(size_t)(a * NR + r) * 256 + t] = s;
    }
}

// ---- K6: transpose outT ((NA*NR) x NC) -> out (NC x (NA*NR)) ----
__global__ __launch_bounds__(256) void k_tr_out(const float* __restrict__ in,
                                                float* __restrict__ outp) {
    __shared__ float tile[32][33];
    int j0 = blockIdx.x * 32;          // (a,r) tile
    int c0 = blockIdx.y * 32;          // channel tile
    int tx = threadIdx.x, ty = threadIdx.y;
    for (int i = 0; i < 32; i += 8)
        tile[ty + i][tx] = in[(size_t)(j0 + ty + i) * NC + c0 + tx];
    __syncthreads();
    for (int i = 0; i < 32; i += 8)
        outp[(size_t)(c0 + ty + i) * (NA * NR) + j0 + tx] = tile[tx][ty + i];
}

extern "C" void kernel_launch(void* const* d_in, const int* in_sizes, int n_in,
                              void* d_out, int out_size, void* d_ws, size_t ws_size,
                              hipStream_t stream) {
    (void)in_sizes; (void)n_in; (void)out_size; (void)ws_size;
    const float* feat = (const float*)d_in[0];
    float* out = (float*)d_out;
    char* ws = (char*)d_ws;

    float*          featT = (float*)(ws + WS_FEATT);
    float*          outT  = (float*)(ws + WS_OUTT);
    unsigned short* plist = (unsigned short*)(ws + WS_PLIST);
    float*          tabs  = (float*)(ws + WS_TABS);
    int*            cnts  = (int*)(ws + WS_CNTS);
    int*            offs  = (int*)(ws + WS_OFFS);

    k_tab    <<<1, 128, 0, stream>>>(tabs);
    k_count  <<<NA, 256, 0, stream>>>(tabs, cnts);
    k_scan   <<<1, 128, 0, stream>>>(cnts, offs);
    k_scatter<<<NA, 256, 0, stream>>>(tabs, offs, plist);
    k_tr_in  <<<dim3(HW / 32, NC / 32), dim3(32, 8), 0, stream>>>(feat, featT);
    k_gather <<<dim3(NR / R_PER_BLK, NA), 256, 0, stream>>>(
        (const float4*)featT, offs, plist, (float4*)outT);
    k_tr_out <<<dim3((NA * NR) / 32, NC / 32), dim3(32, 8), 0, stream>>>(outT, out);
}

// Round 3
// 1110.746 us; speedup vs baseline: 1.1583x; 1.1583x over previous
//
#include <hip/hip_runtime.h>
#include <hip/hip_bf16.h>

// Deep Hough transform, gather/CSR formulation.
// Sizes fixed by setup_inputs(): N=8, C=128, H=W=128, A=R=120.
#define NC    1024
#define HW    16384
#define HH    128
#define WW    128
#define NA    120
#define NR    120
#define PI_D  3.14159265358979323846

// ---------------- workspace layout (bytes) ----------------
#define WS_FEATT   0UL
#define WS_OUTT    67108864UL
#define WS_PLIST   (67108864UL + 58982400UL)            // 126,091,264
#define WS_TABS    (126091264UL + 3932160UL)            // 130,023,424
#define WS_CNTS    (130023424UL + 1024UL)               // 130,024,448
#define WS_OFFS    (130024448UL + 57600UL + 64UL)       // 130,082,112

// ---- K0: cos/sin tables, fp64 exactly like numpy then cast to f32 ----
__global__ void k_tab(float* __restrict__ tabs) {
    int a = threadIdx.x;
    if (a < NA) {
        double itheta = PI_D / (double)NA;
        double diag   = sqrt((double)(HH * HH + WW * WW));      // 181.019...
        double irho   = floor(diag + 1.0) / (double)(NR - 1);   // 182/119
        double ang    = (double)a * itheta;
        tabs[a]       = (float)(cos(ang) / irho);
        tabs[NA + a]  = (float)(sin(ang) / irho);
    }
}

// rho bin for pixel p at angle tabs — MUST match numpy: f32 mul, f32 mul,
// f32 add (no fma contraction), round-half-even, +NR/2, clip.
__device__ __forceinline__ int rho_bin(int p, float tc, float ts) {
#pragma clang fp contract(off)
    int y = p >> 7, x = p & (WW - 1);
    float u = (float)(x - WW / 2) * tc;
    float v = (float)(y - HH / 2) * ts;
    float s = u + v;
    int r = (int)rintf(s) + NR / 2;
    return min(NR - 1, max(0, r));
}

// ---- K1: per-angle histogram of bin counts ----
__global__ __launch_bounds__(256) void k_count(const float* __restrict__ tabs,
                                               int* __restrict__ cnts) {
    __shared__ int cnt[NR];
    int a = blockIdx.x, t = threadIdx.x;
    if (t < NR) cnt[t] = 0;
    __syncthreads();
    float tc = tabs[a], ts = tabs[NA + a];
    for (int p = t; p < HW; p += 256)
        atomicAdd(&cnt[rho_bin(p, tc, ts)], 1);
    __syncthreads();
    if (t < NR) cnts[a * NR + t] = cnt[t];
}

// ---- K2: exclusive scan per angle (one thread per angle) ----
__global__ void k_scan(const int* __restrict__ cnts, int* __restrict__ offs) {
    int a = threadIdx.x;
    if (a < NA) {
        int base = 0;
        for (int r = 0; r < NR; ++r) {
            offs[a * (NR + 1) + r] = base;
            base += cnts[a * NR + r];
        }
        offs[a * (NR + 1) + NR] = base;   // == HW
    }
}

// ---- K3: counting-sort scatter of pixel ids into CSR list ----
__global__ __launch_bounds__(256) void k_scatter(const float* __restrict__ tabs,
                                                 const int* __restrict__ offs,
                                                 unsigned short* __restrict__ plist) {
    __shared__ int cur[NR];
    int a = blockIdx.x, t = threadIdx.x;
    if (t < NR) cur[t] = offs[a * (NR + 1) + t];
    __syncthreads();
    float tc = tabs[a], ts = tabs[NA + a];
    for (int p = t; p < HW; p += 256) {
        int r = rho_bin(p, tc, ts);
        int pos = atomicAdd(&cur[r], 1);
        plist[a * HW + pos] = (unsigned short)p;
    }
}

// ---- K4: transpose feat (NC x HW) -> featT (HW x NC) ----
__global__ __launch_bounds__(256) void k_tr_in(const float* __restrict__ in,
                                               float* __restrict__ outp) {
    __shared__ float tile[32][33];
    int p0 = blockIdx.x * 32;          // pixel tile
    int c0 = blockIdx.y * 32;          // channel tile
    int tx = threadIdx.x, ty = threadIdx.y;   // 32 x 8
    for (int i = 0; i < 32; i += 8)
        tile[ty + i][tx] = in[(size_t)(c0 + ty + i) * HW + p0 + tx];
    __syncthreads();
    for (int i = 0; i < 32; i += 8)
        outp[(size_t)(p0 + ty + i) * NC + c0 + tx] = tile[tx][ty + i];
}

// ---- K5: main gather. block = one (rho, angle) bin; thread t = 4 channels.
// grid = dim3(NR, NA): linear block id n = a*120 + r, and 120 % 8 == 0, so
// XCD = r % 8 -> every angle of a given rho bin lands on ONE XCD, and the
// high-overlap (a,r)/(a+1,r) pairs run ~concurrently there (L2 reuse).
// 8 outstanding dwordx4 loads per thread for MLP.
__global__ __launch_bounds__(256) void k_gather(const float4* __restrict__ featT4,
                                                const int* __restrict__ offs,
                                                const unsigned short* __restrict__ plist,
                                                float4* __restrict__ outT4) {
    const int r = blockIdx.x;
    const int a = blockIdx.y;
    const int t = threadIdx.x;               // 256 threads x float4 = 1024 nc
    const unsigned short* pl = plist + (size_t)a * HW;

    const int k0 = offs[a * (NR + 1) + r];
    const int k1 = offs[a * (NR + 1) + r + 1];

    float4 a0 = {0.f, 0.f, 0.f, 0.f}, a1 = a0, a2 = a0, a3 = a0;
    int k = k0;
    for (; k + 8 <= k1; k += 8) {
        int p0 = pl[k + 0], p1 = pl[k + 1], p2 = pl[k + 2], p3 = pl[k + 3];
        int p4 = pl[k + 4], p5 = pl[k + 5], p6 = pl[k + 6], p7 = pl[k + 7];
        float4 v0 = featT4[(size_t)p0 * 256 + t];
        float4 v1 = featT4[(size_t)p1 * 256 + t];
        float4 v2 = featT4[(size_t)p2 * 256 + t];
        float4 v3 = featT4[(size_t)p3 * 256 + t];
        float4 v4 = featT4[(size_t)p4 * 256 + t];
        float4 v5 = featT4[(size_t)p5 * 256 + t];
        float4 v6 = featT4[(size_t)p6 * 256 + t];
        float4 v7 = featT4[(size_t)p7 * 256 + t];
        a0.x += v0.x; a0.y += v0.y; a0.z += v0.z; a0.w += v0.w;
        a1.x += v1.x; a1.y += v1.y; a1.z += v1.z; a1.w += v1.w;
        a2.x += v2.x; a2.y += v2.y; a2.z += v2.z; a2.w += v2.w;
        a3.x += v3.x; a3.y += v3.y; a3.z += v3.z; a3.w += v3.w;
        a0.x += v4.x; a0.y += v4.y; a0.z += v4.z; a0.w += v4.w;
        a1.x += v5.x; a1.y += v5.y; a1.z += v5.z; a1.w += v5.w;
        a2.x += v6.x; a2.y += v6.y; a2.z += v6.z; a2.w += v6.w;
        a3.x += v7.x; a3.y += v7.y; a3.z += v7.z; a3.w += v7.w;
    }
    for (; k + 4 <= k1; k += 4) {
        int p0 = pl[k + 0], p1 = pl[k + 1], p2 = pl[k + 2], p3 = pl[k + 3];
        float4 v0 = featT4[(size_t)p0 * 256 + t];
        float4 v1 = featT4[(size_t)p1 * 256 + t];
        float4 v2 = featT4[(size_t)p2 * 256 + t];
        float4 v3 = featT4[(size_t)p3 * 256 + t];
        a0.x += v0.x; a0.y += v0.y; a0.z += v0.z; a0.w += v0.w;
        a1.x += v1.x; a1.y += v1.y; a1.z += v1.z; a1.w += v1.w;
        a2.x += v2.x; a2.y += v2.y; a2.z += v2.z; a2.w += v2.w;
        a3.x += v3.x; a3.y += v3.y; a3.z += v3.z; a3.w += v3.w;
    }
    for (; k < k1; ++k) {
        float4 v = featT4[(size_t)pl[k] * 256 + t];
        a0.x += v.x; a0.y += v.y; a0.z += v.z; a0.w += v.w;
    }
    float4 s;
    s.x = (a0.x + a1.x) + (a2.x + a3.x);
    s.y = (a0.y + a1.y) + (a2.y + a3.y);
    s.z = (a0.z + a1.z) + (a2.z + a3.z);
    s.w = (a0.w + a1.w) + (a2.w + a3.w);
    outT4[(size_t)(a * NR + r) * 256 + t] = s;
}

// ---- K6: transpose outT ((NA*NR) x NC) -> out (NC x (NA*NR)) ----
__global__ __launch_bounds__(256) void k_tr_out(const float* __restrict__ in,
                                                float* __restrict__ outp) {
    __shared__ float tile[32][33];
    int j0 = blockIdx.x * 32;          // (a,r) tile
    int c0 = blockIdx.y * 32;          // channel tile
    int tx = threadIdx.x, ty = threadIdx.y;
    for (int i = 0; i < 32; i += 8)
        tile[ty + i][tx] = in[(size_t)(j0 + ty + i) * NC + c0 + tx];
    __syncthreads();
    for (int i = 0; i < 32; i += 8)
        outp[(size_t)(c0 + ty + i) * (NA * NR) + j0 + tx] = tile[tx][ty + i];
}

extern "C" void kernel_launch(void* const* d_in, const int* in_sizes, int n_in,
                              void* d_out, int out_size, void* d_ws, size_t ws_size,
                              hipStream_t stream) {
    (void)in_sizes; (void)n_in; (void)out_size; (void)ws_size;
    const float* feat = (const float*)d_in[0];
    float* out = (float*)d_out;
    char* ws = (char*)d_ws;

    float*          featT = (float*)(ws + WS_FEATT);
    float*          outT  = (float*)(ws + WS_OUTT);
    unsigned short* plist = (unsigned short*)(ws + WS_PLIST);
    float*          tabs  = (float*)(ws + WS_TABS);
    int*            cnts  = (int*)(ws + WS_CNTS);
    int*            offs  = (int*)(ws + WS_OFFS);

    k_tab    <<<1, 128, 0, stream>>>(tabs);
    k_count  <<<NA, 256, 0, stream>>>(tabs, cnts);
    k_scan   <<<1, 128, 0, stream>>>(cnts, offs);
    k_scatter<<<NA, 256, 0, stream>>>(tabs, offs, plist);
    k_tr_in  <<<dim3(HW / 32, NC / 32), dim3(32, 8), 0, stream>>>(feat, featT);
    k_gather <<<dim3(NR, NA), 256, 0, stream>>>(
        (const float4*)featT, offs, plist, (float4*)outT);
    k_tr_out <<<dim3((NA * NR) / 32, NC / 32), dim3(32, 8), 0, stream>>>(outT, out);
}